// Round 7
// baseline (486.228 us; speedup 1.0000x reference)
//
#include <hip/hip_runtime.h>

constexpr int N    = 50000;
constexpr int E    = 800000;
constexpr int CIN  = 128;
constexpr int COUT = 64;
constexpr float SELF_LOOP_W = 2.0f;

constexpr int NB   = (N + 63) / 64;   // 782 buckets of 64 nodes
constexpr int CAP  = 2048;            // slots per bucket (mean load 1024, sigma 32)
constexpr int EPB  = 4096;            // edges per partition block
constexpr int PBLK = (E + EPB - 1) / EPB;   // 196

typedef float vfloat4 __attribute__((ext_vector_type(4)));
typedef int   vint2   __attribute__((ext_vector_type(2)));

// ---------------------------------------------------------------------------
// bucket cursors: bcur[b] = b*CAP
__global__ void init_kernel(int* __restrict__ bcur) {
    int i = blockIdx.x * blockDim.x + threadIdx.x;
    if (i < NB) bcur[i] = i * CAP;
}

// ---------------------------------------------------------------------------
// radix partition: pk[p] = {row | (local_node<<20), bits(ew)} bucketed by col>>6
__global__ __launch_bounds__(256) void partition_kernel(const int* __restrict__ row,
                                                        const int* __restrict__ col,
                                                        const float* __restrict__ ew,
                                                        int* __restrict__ bcur,
                                                        vint2* __restrict__ pk) {
    __shared__ int lhist[NB];
    __shared__ int lbase[NB];
    const int t  = threadIdx.x;
    const int e0 = blockIdx.x * EPB;

    for (int i = t; i < NB; i += 256) lhist[i] = 0;
    __syncthreads();

    #pragma unroll
    for (int k = 0; k < EPB / 256; ++k) {
        int e = e0 + k * 256 + t;
        if (e < E) atomicAdd(&lhist[col[e] >> 6], 1);
    }
    __syncthreads();

    for (int i = t; i < NB; i += 256) {
        int h = lhist[i];
        lbase[i] = (h > 0) ? atomicAdd(&bcur[i], h) : 0;
    }
    __syncthreads();
    for (int i = t; i < NB; i += 256) lhist[i] = 0;
    __syncthreads();

    #pragma unroll
    for (int k = 0; k < EPB / 256; ++k) {
        int e = e0 + k * 256 + t;
        if (e < E) {
            int c   = col[e];
            int bkt = c >> 6;
            int p = lbase[bkt] + atomicAdd(&lhist[bkt], 1);
            if (p < (bkt + 1) * CAP) {          // safety vs capacity overflow
                vint2 v;
                v.x = row[e] | ((c & 63) << 20);
                v.y = __float_as_int(ew[e]);
                pk[p] = v;
            }
        }
    }
}

// ---------------------------------------------------------------------------
// per-bucket degree -> dinv  (dinv[c] = rsqrt(2 + sum ew))
__global__ __launch_bounds__(256) void deg_kernel(const int* __restrict__ bcur,
                                                  const vint2* __restrict__ pk,
                                                  float* __restrict__ dinv) {
    __shared__ float ldeg[64];
    const int t    = threadIdx.x;
    const int b    = blockIdx.x;
    const int base = b * CAP;
    const int cnt  = min(bcur[b] - base, CAP);

    if (t < 64) ldeg[t] = 0.f;
    __syncthreads();
    for (int j = t; j < cnt; j += 256) {
        vint2 v = pk[base + j];
        atomicAdd(&ldeg[v.x >> 20], __int_as_float(v.y));
    }
    __syncthreads();
    int node = b * 64 + t;
    if (t < 64 && node < N) dinv[node] = rsqrtf(SELF_LOOP_W + ldeg[t]);
}

// ---------------------------------------------------------------------------
// pure GEMM: xw = x @ W  (64x64 tile, 4x4 per thread)
__global__ __launch_bounds__(256) void xw_kernel(const float* __restrict__ x,
                                                 const float* __restrict__ W,
                                                 float* __restrict__ xw) {
    __shared__ __align__(16) float xs[64][132];

    const int t    = threadIdx.x;
    const int base = blockIdx.x * 64;

    #pragma unroll
    for (int i = 0; i < 8; ++i) {
        int f4  = i * 256 + t;
        int r   = f4 >> 5;
        int c4  = f4 & 31;
        int node = base + r;
        if (node >= N) node = N - 1;
        vfloat4 v = *(const vfloat4*)(x + (size_t)node * CIN + c4 * 4);
        *(vfloat4*)&xs[r][c4 * 4] = v;
    }
    __syncthreads();

    const int tc = t & 15;
    const int tn = t >> 4;

    float acc[4][4];
    #pragma unroll
    for (int i = 0; i < 4; ++i)
        #pragma unroll
        for (int j = 0; j < 4; ++j) acc[i][j] = 0.f;

    const float* Wp = W + tc * 4;
    #pragma unroll 8
    for (int k = 0; k < CIN; ++k) {
        vfloat4 bv = *(const vfloat4*)(Wp + (size_t)k * COUT);
        float a0 = xs[tn * 4 + 0][k];
        float a1 = xs[tn * 4 + 1][k];
        float a2 = xs[tn * 4 + 2][k];
        float a3 = xs[tn * 4 + 3][k];
        #pragma unroll
        for (int j = 0; j < 4; ++j) {
            acc[0][j] += a0 * bv[j];
            acc[1][j] += a1 * bv[j];
            acc[2][j] += a2 * bv[j];
            acc[3][j] += a3 * bv[j];
        }
    }

    #pragma unroll
    for (int i = 0; i < 4; ++i) {
        int node = base + tn * 4 + i;
        if (node >= N) continue;
        vfloat4 xv;
        #pragma unroll
        for (int j = 0; j < 4; ++j) xv[j] = acc[i][j];
        *(vfloat4*)(xw + (size_t)node * COUT + tc * 4) = xv;
    }
}

// ---------------------------------------------------------------------------
// per-bucket aggregation into LDS accumulator; epilogue folds self-loop + bias
__global__ __launch_bounds__(256) void aggregate_kernel(const int* __restrict__ bcur,
                                                        const vint2* __restrict__ pk,
                                                        const float* __restrict__ dinv,
                                                        const float* __restrict__ xw,
                                                        const float* __restrict__ bias,
                                                        float* __restrict__ out) {
    __shared__ float acc[64 * 64];      // 16 KB: [local node][channel]
    __shared__ vint2 srec[256];

    const int t    = threadIdx.x;
    const int lane = t & 63;
    const int wv   = t >> 6;
    const int b    = blockIdx.x;
    const int base = b * CAP;
    const int cnt  = min(bcur[b] - base, CAP);

    #pragma unroll
    for (int i = 0; i < 16; ++i) acc[i * 256 + t] = 0.f;
    __syncthreads();

    for (int j0 = 0; j0 < cnt; j0 += 256) {
        int m = min(256, cnt - j0);
        if (t < m) srec[t] = pk[base + j0 + t];
        __syncthreads();

        int lo = wv * 64;
        int hi = min(m, lo + 64);
        int i  = lo;
        for (; i + 4 <= hi; i += 4) {
            vint2 r0 = srec[i], r1 = srec[i + 1], r2 = srec[i + 2], r3 = srec[i + 3];
            int a0 = r0.x & 0xFFFFF, a1 = r1.x & 0xFFFFF;
            int a2 = r2.x & 0xFFFFF, a3 = r3.x & 0xFFFFF;
            float n0 = __int_as_float(r0.y) * dinv[a0];
            float n1 = __int_as_float(r1.y) * dinv[a1];
            float n2 = __int_as_float(r2.y) * dinv[a2];
            float n3 = __int_as_float(r3.y) * dinv[a3];
            float v0 = xw[(size_t)a0 * COUT + lane];
            float v1 = xw[(size_t)a1 * COUT + lane];
            float v2 = xw[(size_t)a2 * COUT + lane];
            float v3 = xw[(size_t)a3 * COUT + lane];
            atomicAdd(&acc[(r0.x >> 20) * 64 + lane], n0 * v0);
            atomicAdd(&acc[(r1.x >> 20) * 64 + lane], n1 * v1);
            atomicAdd(&acc[(r2.x >> 20) * 64 + lane], n2 * v2);
            atomicAdd(&acc[(r3.x >> 20) * 64 + lane], n3 * v3);
        }
        for (; i < hi; ++i) {
            vint2 r0 = srec[i];
            int   a0 = r0.x & 0xFFFFF;
            float n0 = __int_as_float(r0.y) * dinv[a0];
            atomicAdd(&acc[(r0.x >> 20) * 64 + lane], n0 * xw[(size_t)a0 * COUT + lane]);
        }
        __syncthreads();
    }

    float bl = bias[lane];
    #pragma unroll
    for (int idx = wv; idx < 64; idx += 4) {
        int node = b * 64 + idx;
        if (node < N) {
            float dc = dinv[node];
            float xv = xw[(size_t)node * COUT + lane];
            out[(size_t)node * COUT + lane] =
                dc * acc[idx * 64 + lane] + SELF_LOOP_W * dc * dc * xv + bl;
        }
    }
}

// ---------------------------------------------------------------------------
extern "C" void kernel_launch(void* const* d_in, const int* in_sizes, int n_in,
                              void* d_out, int out_size, void* d_ws, size_t ws_size,
                              hipStream_t stream) {
    const float* x  = (const float*)d_in[0];
    const int*   ei = (const int*)d_in[1];   // [2, E] int32
    const float* ew = (const float*)d_in[2];
    const float* W  = (const float*)d_in[3];
    const float* b  = (const float*)d_in[4];
    float* out = (float*)d_out;

    // ws layout
    float* xw   = (float*)d_ws;                      // N*COUT floats (12.8 MB)
    float* dinv = xw + (size_t)N * COUT;             // N
    int*   bcur = (int*)(dinv + N);                  // NB
    vint2* pk   = (vint2*)(bcur + NB);               // NB*CAP records (12.8 MB)

    const int* rowp = ei;
    const int* colp = ei + E;

    init_kernel     <<<(NB + 255) / 256, 256, 0, stream>>>(bcur);
    partition_kernel<<<PBLK, 256, 0, stream>>>(rowp, colp, ew, bcur, pk);
    xw_kernel       <<<NB, 256, 0, stream>>>(x, W, xw);
    deg_kernel      <<<NB, 256, 0, stream>>>(bcur, pk, dinv);
    aggregate_kernel<<<NB, 256, 0, stream>>>(bcur, pk, dinv, xw, b, out);
}

// Round 8
// 475.687 us; speedup vs baseline: 1.0222x; 1.0222x over previous
//
#include <hip/hip_runtime.h>

constexpr int N    = 50000;
constexpr int E    = 800000;
constexpr int CIN  = 128;
constexpr int COUT = 64;
constexpr float SELF_LOOP_W = 2.0f;

constexpr int NB   = (N + 63) / 64;   // 782 buckets of 64 nodes
constexpr int CAP  = 2048;            // slots per bucket (mean 1024, sigma ~32)
constexpr int EPB  = 2048;            // edges per partition block
constexpr int PBLK = (E + EPB - 1) / EPB;   // 391

typedef float vfloat4 __attribute__((ext_vector_type(4)));
typedef int   vint2   __attribute__((ext_vector_type(2)));

// ---------------------------------------------------------------------------
__global__ void init_kernel(int* __restrict__ bcur) {
    int i = blockIdx.x * blockDim.x + threadIdx.x;
    if (i < NB) bcur[i] = i * CAP;
}

// ---------------------------------------------------------------------------
// radix partition: pk[p] = {row | (local_node<<20), bits(ew)} bucketed by col>>6
__global__ __launch_bounds__(512) void partition_kernel(const int* __restrict__ row,
                                                        const int* __restrict__ col,
                                                        const float* __restrict__ ew,
                                                        int* __restrict__ bcur,
                                                        vint2* __restrict__ pk) {
    __shared__ int lhist[NB];
    __shared__ int lbase[NB];
    const int t  = threadIdx.x;
    const int e0 = blockIdx.x * EPB;

    for (int i = t; i < NB; i += 512) lhist[i] = 0;
    __syncthreads();

    #pragma unroll
    for (int k = 0; k < EPB / 512; ++k) {
        int e = e0 + k * 512 + t;
        if (e < E) atomicAdd(&lhist[col[e] >> 6], 1);
    }
    __syncthreads();

    for (int i = t; i < NB; i += 512) {
        int h = lhist[i];
        lbase[i] = (h > 0) ? atomicAdd(&bcur[i], h) : 0;
    }
    __syncthreads();
    for (int i = t; i < NB; i += 512) lhist[i] = 0;
    __syncthreads();

    #pragma unroll
    for (int k = 0; k < EPB / 512; ++k) {
        int e = e0 + k * 512 + t;
        if (e < E) {
            int c   = col[e];
            int bkt = c >> 6;
            int p = lbase[bkt] + atomicAdd(&lhist[bkt], 1);
            if (p < (bkt + 1) * CAP) {          // safety vs capacity overflow
                vint2 v;
                v.x = row[e] | ((c & 63) << 20);
                v.y = __float_as_int(ew[e]);
                pk[p] = v;
            }
        }
    }
}

// ---------------------------------------------------------------------------
// per-bucket degree -> dinv  (dinv[c] = rsqrt(2 + sum ew))
__global__ __launch_bounds__(512) void deg_kernel(const int* __restrict__ bcur,
                                                  const vint2* __restrict__ pk,
                                                  float* __restrict__ dinv) {
    __shared__ float ldeg[64];
    const int t    = threadIdx.x;
    const int b    = blockIdx.x;
    const int base = b * CAP;
    const int cnt  = min(bcur[b] - base, CAP);

    if (t < 64) ldeg[t] = 0.f;
    __syncthreads();
    for (int j = t; j < cnt; j += 512) {
        vint2 v = pk[base + j];
        atomicAdd(&ldeg[(v.x >> 20) & 63], __int_as_float(v.y));
    }
    __syncthreads();
    int node = b * 64 + t;
    if (t < 64 && node < N) dinv[node] = rsqrtf(SELF_LOOP_W + ldeg[t]);
}

// ---------------------------------------------------------------------------
// pure GEMM: xw = x @ W  (64x64 tile, 4x4 per thread)
__global__ __launch_bounds__(256) void xw_kernel(const float* __restrict__ x,
                                                 const float* __restrict__ W,
                                                 float* __restrict__ xw) {
    __shared__ __align__(16) float xs[64][132];

    const int t    = threadIdx.x;
    const int base = blockIdx.x * 64;

    #pragma unroll
    for (int i = 0; i < 8; ++i) {
        int f4  = i * 256 + t;
        int r   = f4 >> 5;
        int c4  = f4 & 31;
        int node = base + r;
        if (node >= N) node = N - 1;
        vfloat4 v = *(const vfloat4*)(x + (size_t)node * CIN + c4 * 4);
        *(vfloat4*)&xs[r][c4 * 4] = v;
    }
    __syncthreads();

    const int tc = t & 15;
    const int tn = t >> 4;

    float acc[4][4];
    #pragma unroll
    for (int i = 0; i < 4; ++i)
        #pragma unroll
        for (int j = 0; j < 4; ++j) acc[i][j] = 0.f;

    const float* Wp = W + tc * 4;
    #pragma unroll 8
    for (int k = 0; k < CIN; ++k) {
        vfloat4 bv = *(const vfloat4*)(Wp + (size_t)k * COUT);
        float a0 = xs[tn * 4 + 0][k];
        float a1 = xs[tn * 4 + 1][k];
        float a2 = xs[tn * 4 + 2][k];
        float a3 = xs[tn * 4 + 3][k];
        #pragma unroll
        for (int j = 0; j < 4; ++j) {
            acc[0][j] += a0 * bv[j];
            acc[1][j] += a1 * bv[j];
            acc[2][j] += a2 * bv[j];
            acc[3][j] += a3 * bv[j];
        }
    }

    #pragma unroll
    for (int i = 0; i < 4; ++i) {
        int node = base + tn * 4 + i;
        if (node >= N) continue;
        vfloat4 xv;
        #pragma unroll
        for (int j = 0; j < 4; ++j) xv[j] = acc[i][j];
        *(vfloat4*)(xw + (size_t)node * COUT + tc * 4) = xv;
    }
}

// ---------------------------------------------------------------------------
// per-bucket aggregation into LDS accumulator; 8 waves, unroll-8 for MLP.
__global__ __launch_bounds__(512, 6) void aggregate_kernel(const int* __restrict__ bcur,
                                                           const vint2* __restrict__ pk,
                                                           const float* __restrict__ dinv,
                                                           const float* __restrict__ xw,
                                                           const float* __restrict__ bias,
                                                           float* __restrict__ out) {
    __shared__ float acc[64 * 64];      // 16 KB: [local node][channel]
    __shared__ vint2 srec[512];

    const int t    = threadIdx.x;
    const int lane = t & 63;
    const int wv   = t >> 6;            // 0..7
    const int b    = blockIdx.x;
    const int base = b * CAP;
    const int cnt  = min(bcur[b] - base, CAP);

    #pragma unroll
    for (int i = 0; i < 8; ++i) acc[i * 512 + t] = 0.f;
    __syncthreads();

    for (int j0 = 0; j0 < cnt; j0 += 512) {
        int m = min(512, cnt - j0);
        if (t < m) srec[t] = pk[base + j0 + t];
        __syncthreads();

        int lo = wv * 64;
        int hi = min(m, lo + 64);
        int i  = lo;
        for (; i + 8 <= hi; i += 8) {
            int   a[8]; int ln[8]; float n[8]; float v[8];
            #pragma unroll
            for (int u = 0; u < 8; ++u) {
                vint2 r = srec[i + u];
                a[u]  = r.x & 0xFFFFF;
                ln[u] = (r.x >> 20) & 63;
                n[u]  = __int_as_float(r.y);
            }
            #pragma unroll
            for (int u = 0; u < 8; ++u) n[u] *= dinv[a[u]];
            #pragma unroll
            for (int u = 0; u < 8; ++u) v[u] = xw[(size_t)a[u] * COUT + lane];
            #pragma unroll
            for (int u = 0; u < 8; ++u)
                atomicAdd(&acc[ln[u] * 64 + lane], n[u] * v[u]);
        }
        for (; i < hi; ++i) {
            vint2 r = srec[i];
            int   a0 = r.x & 0xFFFFF;
            float n0 = __int_as_float(r.y) * dinv[a0];
            atomicAdd(&acc[((r.x >> 20) & 63) * 64 + lane],
                      n0 * xw[(size_t)a0 * COUT + lane]);
        }
        __syncthreads();
    }

    float bl = bias[lane];
    #pragma unroll
    for (int idx = wv; idx < 64; idx += 8) {
        int node = b * 64 + idx;
        if (node < N) {
            float dc = dinv[node];
            float xv = xw[(size_t)node * COUT + lane];
            out[(size_t)node * COUT + lane] =
                dc * acc[idx * 64 + lane] + SELF_LOOP_W * dc * dc * xv + bl;
        }
    }
}

// ---------------------------------------------------------------------------
extern "C" void kernel_launch(void* const* d_in, const int* in_sizes, int n_in,
                              void* d_out, int out_size, void* d_ws, size_t ws_size,
                              hipStream_t stream) {
    const float* x  = (const float*)d_in[0];
    const int*   ei = (const int*)d_in[1];   // [2, E] int32
    const float* ew = (const float*)d_in[2];
    const float* W  = (const float*)d_in[3];
    const float* b  = (const float*)d_in[4];
    float* out = (float*)d_out;

    // ws layout
    float* xw   = (float*)d_ws;                      // N*COUT floats (12.8 MB)
    float* dinv = xw + (size_t)N * COUT;             // N
    int*   bcur = (int*)(dinv + N);                  // NB
    vint2* pk   = (vint2*)(bcur + NB);               // NB*CAP records (12.8 MB)

    const int* rowp = ei;
    const int* colp = ei + E;

    init_kernel     <<<(NB + 255) / 256, 256, 0, stream>>>(bcur);
    partition_kernel<<<PBLK, 512, 0, stream>>>(rowp, colp, ew, bcur, pk);
    xw_kernel       <<<NB, 256, 0, stream>>>(x, W, xw);
    deg_kernel      <<<NB, 512, 0, stream>>>(bcur, pk, dinv);
    aggregate_kernel<<<NB, 512, 0, stream>>>(bcur, pk, dinv, xw, b, out);
}